// Round 25
// baseline (94.027 us; speedup 1.0000x reference)
//
#include <hip/hip_runtime.h>
#include <hip/hip_fp16.h>
#include <math.h>

#define N_NODES 100000
#define N_EDGES 1000000
#define IN_DIM 64
#define OUT_DIM 64
#define CAP 32        // per-dst slots = 2 cache lines
#define NB_BKT 512    // binning buckets; one binB block per bucket
#define DPB 196       // dsts per bucket; 512*196 >= N
#define QB 2304       // records per bucket (mean 1953 + 8 sigma)
#define BINA_BLOCKS 256    // 512 threads each; chunk 3907 (r22 proven)
#define BINA_CHUNK 3907
#define PREP_BLOCKS 3125   // (N*16)/512 4-elem units

typedef __attribute__((ext_vector_type(8)))  _Float16 f16x8;
typedef __attribute__((ext_vector_type(16))) float f32x16;
typedef __attribute__((ext_vector_type(8)))  unsigned short u16x8;
typedef __attribute__((ext_vector_type(4)))  unsigned short u16x4;

__device__ __forceinline__ __half2 asH2(unsigned int u) {
    union { unsigned int u; __half2 h; } c; c.u = u; return c.h;
}
__device__ __forceinline__ unsigned int asU32(__half2 h) {
    union { unsigned int u; __half2 h; } c; c.h = h; return c.u;
}

// ---------------------------------------------------------------------------
// Merged prepA (r24 post-mortem: prep and binA are independent; prep is
// BW-bound, binA latency/atomic-bound -> co-schedule in one launch).
// Blocks [0,256): binA (r22/r24 proven body). Blocks [256,..): prep
// (W -> f16 single, x -> f16 rows). qcnt zeroed by hipMemsetAsync.
// ---------------------------------------------------------------------------
__global__ __launch_bounds__(512) void k_prepA(
    const float* __restrict__ x,
    const float* __restrict__ weight, const float* __restrict__ root,
    const int* __restrict__ ei, const int* __restrict__ et,
    unsigned short* __restrict__ xh, unsigned short* __restrict__ wt,
    int* __restrict__ qcnt, unsigned int* __restrict__ queue)
{
    __shared__ int hist[NB_BKT], base[NB_BKT], cur[NB_BKT];
    int tid = threadIdx.x;

    if (blockIdx.x < BINA_BLOCKS) {
        // ---- binA ----
        for (int b = tid; b < NB_BKT; b += 512) { hist[b] = 0; cur[b] = 0; }
        __syncthreads();
        int b0 = blockIdx.x * BINA_CHUNK;
        int b1 = b0 + BINA_CHUNK; if (b1 > N_EDGES) b1 = N_EDGES;
        for (int e = b0 + tid; e < b1; e += 512)
            atomicAdd(&hist[ei[N_EDGES + e] / DPB], 1);
        __syncthreads();
        for (int b = tid; b < NB_BKT; b += 512)
            base[b] = atomicAdd(&qcnt[b], hist[b]);
        __syncthreads();
        for (int e = b0 + tid; e < b1; e += 512) {
            int d = ei[N_EDGES + e];
            int bkt = d / DPB;
            int ld = d - bkt * DPB;                    // 0..195
            int pos = base[bkt] + atomicAdd(&cur[bkt], 1);
            if (pos < QB) {
                queue[(size_t)bkt * QB + pos] =
                    ((unsigned)ld << 19) | (unsigned)((ei[e] << 2) | (et[e] & 3));
            }
        }
    } else {
        // ---- prep ----
        int u = (blockIdx.x - BINA_BLOCKS) * 512 + tid;   // 4-elem unit
        if (u < 64 * 320) {                               // W -> f16 [n][k]
            int n = u / 320, k = u - n * 320;
            float v = (k < 256) ? weight[k * 64 + n] : root[(k - 256) * 64 + n];
            union { __half h; unsigned short s; } c; c.h = __float2half_rn(v);
            wt[u] = c.s;
        }
        if (u < N_NODES * 16) {
            float4 v = *(const float4*)(x + (size_t)u * 4);
            uint2 st;
            st.x = asU32(__floats2half2_rn(v.x, v.y));
            st.y = asU32(__floats2half2_rn(v.z, v.w));
            *(uint2*)(xh + (size_t)u * 4) = st;
        }
    }
}

// ---------------------------------------------------------------------------
// binB (r22 proven single-pass): one block per bucket; decode 4B records;
// assemble slot rows in LDS; dense writeout.
// ---------------------------------------------------------------------------
__global__ __launch_bounds__(256) void k_binB(const int* __restrict__ qcnt,
                                              const unsigned int* __restrict__ queue,
                                              int* __restrict__ cnt,
                                              int* __restrict__ slots) {
    __shared__ int lcnt[DPB];
    __shared__ int lslot[DPB * CAP];   // 25 KB
    int tid = threadIdx.x;
    int bkt = blockIdx.x;
    int d0 = bkt * DPB;
    for (int i = tid; i < DPB; i += 256) lcnt[i] = 0;
    __syncthreads();
    int n = qcnt[bkt]; if (n > QB) n = QB;
    const unsigned int* q = queue + (size_t)bkt * QB;
    for (int i = tid; i < n; i += 256) {
        unsigned int r = q[i];
        int d = (int)(r >> 19);                 // local_d 0..DPB-1
        int pos = atomicAdd(&lcnt[d], 1);
        if (pos < CAP) lslot[(d << 5) + pos] = (int)(r & 0x7ffffu);
    }
    __syncthreads();
    for (int i = tid; i < DPB; i += 256) {
        int g = d0 + i;
        if (g < N_NODES) cnt[g] = lcnt[i];
    }
    for (int i = tid; i < DPB * CAP / 4; i += 256) {
        int g0 = d0 * CAP + i * 4;
        if (g0 < N_NODES * CAP) {
            int4 v = *(const int4*)&lslot[i * 4];
            *(int4*)&slots[g0] = v;
        }
    }
}

// ---------------------------------------------------------------------------
// Gather (r22/r24 proven form; f16 agg store): one wave per node; 128B slot
// row loaded once coalesced; slot values via __shfl with wave-uniform trip
// count (all lanes active through every shuffle); validity folded into
// relation mask.
// ---------------------------------------------------------------------------
__global__ __launch_bounds__(256) void k_gather(
    const int* __restrict__ cnt, const int* __restrict__ slots,
    const unsigned short* __restrict__ xh, unsigned short* __restrict__ agg)
{
    int wv = threadIdx.x >> 6, ln = threadIdx.x & 63;
    int node = blockIdx.x * 4 + wv;
    int es = ln >> 4;          // edge slot 0..3 (also output rel)
    int fq = ln & 15;          // feature quarter 0..15

    int deg = cnt[node];
    int m = (deg < CAP) ? deg : CAP;
    float inv = 1.0f / fmaxf((float)deg, 1.0f);

    int sv = slots[(node << 5) + (ln & 31)];   // coalesced full-row load

    __half2 a0_01 = asH2(0), a0_23 = asH2(0);
    __half2 a1_01 = asH2(0), a1_23 = asH2(0);
    __half2 a2_01 = asH2(0), a2_23 = asH2(0);
    __half2 a3_01 = asH2(0), a3_23 = asH2(0);

    int T = (m + 3) >> 2;                      // wave-uniform trip count
    for (int t = 0; t < T; ++t) {
        int i = es + (t << 2);                 // es+4t <= 31 always
        int p = __shfl(sv, i);                 // all lanes active
        bool valid = (i < m);
        if (!valid) p = 0;                     // clamp: no OOB xh read
        int r = p & 3;
        uint2 v = *(const uint2*)(xh + ((size_t)(p >> 2) << 6) + (fq << 2));
        __half2 h01 = asH2(v.x), h23 = asH2(v.y);
        __half2 m0 = asH2((valid && r == 0) ? 0x3C003C00u : 0u);
        __half2 m1 = asH2((valid && r == 1) ? 0x3C003C00u : 0u);
        __half2 m2 = asH2((valid && r == 2) ? 0x3C003C00u : 0u);
        __half2 m3 = asH2((valid && r == 3) ? 0x3C003C00u : 0u);
        a0_01 = __hfma2(h01, m0, a0_01); a0_23 = __hfma2(h23, m0, a0_23);
        a1_01 = __hfma2(h01, m1, a1_01); a1_23 = __hfma2(h23, m1, a1_23);
        a2_01 = __hfma2(h01, m2, a2_01); a2_23 = __hfma2(h23, m2, a2_23);
        a3_01 = __hfma2(h01, m3, a3_01); a3_23 = __hfma2(h23, m3, a3_23);
    }

#define REDH(a)                                                        \
    a = __hadd2(a, asH2(__shfl_xor(asU32(a), 16)));                    \
    a = __hadd2(a, asH2(__shfl_xor(asU32(a), 32)));
    REDH(a0_01) REDH(a0_23) REDH(a1_01) REDH(a1_23)
    REDH(a2_01) REDH(a2_23) REDH(a3_01) REDH(a3_23)
#undef REDH

    __half2 w01 = a0_01, w23 = a0_23;
    if (es == 1)      { w01 = a1_01; w23 = a1_23; }
    else if (es == 2) { w01 = a2_01; w23 = a2_23; }
    else if (es == 3) { w01 = a3_01; w23 = a3_23; }
    float2 f01 = __half22float2(w01);
    float2 f23 = __half22float2(w23);
    uint2 st;
    st.x = asU32(__floats2half2_rn(f01.x * inv, f01.y * inv));
    st.y = asU32(__floats2half2_rn(f23.x * inv, f23.y * inv));
    *(uint2*)(agg + (size_t)node * 256 + (ln << 2)) = st;   // k = es*64 + fq*4
}

// ---------------------------------------------------------------------------
// MFMA GEMM (f16 single pass, r24 proven): tile 128 nodes x 64 outs, 4 waves.
// A = agg/xh f16, B = wt f16; v_mfma_f32_32x32x16_f16.
// LDS rows 128B, byte ^= (row&7)<<4 swizzle on write & frag read.
// ---------------------------------------------------------------------------
__global__ __launch_bounds__(256) void k_gemm(
    const unsigned short* __restrict__ agg,
    const unsigned short* __restrict__ xh,
    const unsigned short* __restrict__ wt,
    const float* __restrict__ bias, float* __restrict__ out)
{
    __shared__ short As[128 * 64];   // [row][k] f16, swizzled (16 KB)
    __shared__ short Bs[64 * 64];    // [n][k] f16, swizzled   (8 KB)

    int tid = threadIdx.x;
    int n0 = blockIdx.x * 128;
    int lane = tid & 63, wv = tid >> 6;
    int lr = lane & 31, g = lane >> 5;

    f32x16 acc0 = {}, acc1 = {};

    for (int kc = 0; kc < 5; ++kc) {
        if (kc) __syncthreads();
        // stage A: 128 rows x 64 k = 16 KB
        #pragma unroll
        for (int i = 0; i < 4; ++i) {
            int u = i * 256 + tid;
            int row = u >> 3, i16 = u & 7;
            int node = n0 + row;
            if (node > N_NODES - 1) node = N_NODES - 1;   // clamp (epilogue guards)
            const unsigned short* src = (kc < 4)
                ? (agg + (size_t)node * 256 + kc * 64)
                : (xh + (size_t)node * 64);
            u16x8 v = *(const u16x8*)(src + i16 * 8);
            int off = row * 128 + ((i16 * 16) ^ ((row & 7) << 4));
            *(u16x8*)((char*)As + off) = v;
        }
        // stage B: 64 n x 64 k
        #pragma unroll
        for (int i = 0; i < 2; ++i) {
            int u = i * 256 + tid;
            int n = u >> 3, i16 = u & 7;
            size_t s = (size_t)n * 320 + kc * 64 + i16 * 8;
            int off = n * 128 + ((i16 * 16) ^ ((n & 7) << 4));
            *(u16x8*)((char*)Bs + off) = *(const u16x8*)(wt + s);
        }
        __syncthreads();
        int ar = wv * 32 + lr;
        #pragma unroll
        for (int kst = 0; kst < 4; ++kst) {
            int kb = kst * 32 + g * 16;               // byte offset in 128B row
            int offA = ar * 128 + (kb ^ ((ar & 7) << 4));
            int offB = lr * 128 + (kb ^ ((lr & 7) << 4));
            f16x8 ah = *(const f16x8*)((const char*)As + offA);
            f16x8 b0 = *(const f16x8*)((const char*)Bs + offB);
            f16x8 b1 = *(const f16x8*)((const char*)Bs + offB + 32 * 128);
            acc0 = __builtin_amdgcn_mfma_f32_32x32x16_f16(ah, b0, acc0, 0, 0, 0);
            acc1 = __builtin_amdgcn_mfma_f32_32x32x16_f16(ah, b1, acc1, 0, 0, 0);
        }
    }

    // epilogue: C/D layout col=lane&31, row=(reg&3)+8*(reg>>2)+4*g (m74/m101)
    float b0 = bias[lr], b1 = bias[32 + lr];
    #pragma unroll
    for (int r = 0; r < 16; ++r) {
        int rowl = (r & 3) + ((r >> 2) << 3) + (g << 2);
        int node = n0 + wv * 32 + rowl;
        if (node < N_NODES) {
            out[(size_t)node * 64 + lr]      = tanhf(acc0[r] + b0);
            out[(size_t)node * 64 + 32 + lr] = tanhf(acc1[r] + b1);
        }
    }
}

extern "C" void kernel_launch(void* const* d_in, const int* in_sizes, int n_in,
                              void* d_out, int out_size, void* d_ws, size_t ws_size,
                              hipStream_t stream) {
    const float* x      = (const float*)d_in[0];
    const int*   ei     = (const int*)d_in[1];   // [2, E]
    const int*   et     = (const int*)d_in[2];   // [E]
    const float* weight = (const float*)d_in[3]; // [4,64,64]
    const float* root   = (const float*)d_in[4]; // [64,64]
    const float* bias   = (const float*)d_in[5]; // [64]
    float* out = (float*)d_out;

    // d_ws layout (~82 MB):
    unsigned short* agg = (unsigned short*)d_ws;            // N*256 f16 (51.2 MB)
    unsigned short* xh  = agg + (size_t)N_NODES * 256;      // N*64 f16  (12.8 MB)
    unsigned short* wt  = xh + (size_t)N_NODES * 64;        // 64*320 f16
    int* cnt   = (int*)(wt + 64 * 320);                     // N ints (0.4 MB)
    int* slots = cnt + N_NODES;                             // N*CAP ints (12.8 MB)
    int* qcnt  = slots + (size_t)N_NODES * CAP;             // 512 ints
    unsigned int* queue = (unsigned int*)(qcnt + NB_BKT);   // 512*2304 u32 (4.7 MB)

    hipMemsetAsync(qcnt, 0, NB_BKT * sizeof(int), stream);
    k_prepA<<<BINA_BLOCKS + PREP_BLOCKS, 512, 0, stream>>>(
        x, weight, root, ei, et, xh, wt, qcnt, queue);
    k_binB<<<NB_BKT, 256, 0, stream>>>(qcnt, queue, cnt, slots);
    k_gather<<<N_NODES / 4, 256, 0, stream>>>(cnt, slots, xh, agg);
    k_gemm<<<(N_NODES + 127) / 128, 256, 0, stream>>>(agg, xh, wt, bias, out);
}

// Round 26
// 85.019 us; speedup vs baseline: 1.1059x; 1.1059x over previous
//
#include <hip/hip_runtime.h>
#include <hip/hip_fp16.h>
#include <math.h>

#define N_NODES 100000
#define N_EDGES 1000000
#define IN_DIM 64
#define OUT_DIM 64
#define CAP 32        // per-dst slots = 2 cache lines
#define NB_BKT 512    // binning buckets; one binB block per bucket
#define DPB 196       // dsts per bucket; 512*196 >= N
#define QB 2304       // records per bucket (mean 1953 + 8 sigma)
#define BINA_BLOCKS 256    // 512 threads each; chunk 3907 (r22 proven)
#define BINA_CHUNK 3907
#define PREP_BLOCKS 3125   // (N*16)/512 4-elem units

typedef __attribute__((ext_vector_type(8)))  _Float16 f16x8;
typedef __attribute__((ext_vector_type(16))) float f32x16;
typedef __attribute__((ext_vector_type(8)))  unsigned short u16x8;
typedef __attribute__((ext_vector_type(4)))  unsigned short u16x4;

__device__ __forceinline__ __half2 asH2(unsigned int u) {
    union { unsigned int u; __half2 h; } c; c.u = u; return c.h;
}
__device__ __forceinline__ unsigned int asU32(__half2 h) {
    union { unsigned int u; __half2 h; } c; c.h = h; return c.u;
}

// ---------------------------------------------------------------------------
// Merged prepA: blocks [0,256) = binA (r22 proven body); rest = prep
// (W -> f16, x -> f16 rows). qcnt zeroed by hipMemsetAsync.
// ---------------------------------------------------------------------------
__global__ __launch_bounds__(512) void k_prepA(
    const float* __restrict__ x,
    const float* __restrict__ weight, const float* __restrict__ root,
    const int* __restrict__ ei, const int* __restrict__ et,
    unsigned short* __restrict__ xh, unsigned short* __restrict__ wt,
    int* __restrict__ qcnt, unsigned int* __restrict__ queue)
{
    __shared__ int hist[NB_BKT], base[NB_BKT], cur[NB_BKT];
    int tid = threadIdx.x;

    if (blockIdx.x < BINA_BLOCKS) {
        // ---- binA ----
        for (int b = tid; b < NB_BKT; b += 512) { hist[b] = 0; cur[b] = 0; }
        __syncthreads();
        int b0 = blockIdx.x * BINA_CHUNK;
        int b1 = b0 + BINA_CHUNK; if (b1 > N_EDGES) b1 = N_EDGES;
        for (int e = b0 + tid; e < b1; e += 512)
            atomicAdd(&hist[ei[N_EDGES + e] / DPB], 1);
        __syncthreads();
        for (int b = tid; b < NB_BKT; b += 512)
            base[b] = atomicAdd(&qcnt[b], hist[b]);
        __syncthreads();
        for (int e = b0 + tid; e < b1; e += 512) {
            int d = ei[N_EDGES + e];
            int bkt = d / DPB;
            int ld = d - bkt * DPB;                    // 0..195
            int pos = base[bkt] + atomicAdd(&cur[bkt], 1);
            if (pos < QB) {
                queue[(size_t)bkt * QB + pos] =
                    ((unsigned)ld << 19) | (unsigned)((ei[e] << 2) | (et[e] & 3));
            }
        }
    } else {
        // ---- prep ----
        int u = (blockIdx.x - BINA_BLOCKS) * 512 + tid;   // 4-elem unit
        if (u < 64 * 320) {                               // W -> f16 [n][k]
            int n = u / 320, k = u - n * 320;
            float v = (k < 256) ? weight[k * 64 + n] : root[(k - 256) * 64 + n];
            union { __half h; unsigned short s; } c; c.h = __float2half_rn(v);
            wt[u] = c.s;
        }
        if (u < N_NODES * 16) {
            float4 v = *(const float4*)(x + (size_t)u * 4);
            uint2 st;
            st.x = asU32(__floats2half2_rn(v.x, v.y));
            st.y = asU32(__floats2half2_rn(v.z, v.w));
            *(uint2*)(xh + (size_t)u * 4) = st;
        }
    }
}

// ---------------------------------------------------------------------------
// binB (r22 proven single-pass): one block per bucket; decode 4B records;
// assemble slot rows in LDS; dense writeout.
// ---------------------------------------------------------------------------
__global__ __launch_bounds__(256) void k_binB(const int* __restrict__ qcnt,
                                              const unsigned int* __restrict__ queue,
                                              int* __restrict__ cnt,
                                              int* __restrict__ slots) {
    __shared__ int lcnt[DPB];
    __shared__ int lslot[DPB * CAP];   // 25 KB
    int tid = threadIdx.x;
    int bkt = blockIdx.x;
    int d0 = bkt * DPB;
    for (int i = tid; i < DPB; i += 256) lcnt[i] = 0;
    __syncthreads();
    int n = qcnt[bkt]; if (n > QB) n = QB;
    const unsigned int* q = queue + (size_t)bkt * QB;
    for (int i = tid; i < n; i += 256) {
        unsigned int r = q[i];
        int d = (int)(r >> 19);                 // local_d 0..DPB-1
        int pos = atomicAdd(&lcnt[d], 1);
        if (pos < CAP) lslot[(d << 5) + pos] = (int)(r & 0x7ffffu);
    }
    __syncthreads();
    for (int i = tid; i < DPB; i += 256) {
        int g = d0 + i;
        if (g < N_NODES) cnt[g] = lcnt[i];
    }
    for (int i = tid; i < DPB * CAP / 4; i += 256) {
        int g0 = d0 * CAP + i * 4;
        if (g0 < N_NODES * CAP) {
            int4 v = *(const int4*)&lslot[i * 4];
            *(int4*)&slots[g0] = v;
        }
    }
}

// ---------------------------------------------------------------------------
// Gather (r25 post-mortem: VGPR=16 => ~1-2 loads in flight; 41us pinned
// across 5 instruction-mix variants => latency/MLP-bound, not VALU-bound).
// BATCHED-4 loads: wave-uniform batches of 4 t's issue 4 independent uint2
// loads back-to-back (4x MLP). Batch 1 unconditional (deg<=16, ~97% of
// nodes); batch 2 iff m>16 (wave-uniform). Invalid t's clamp p=0 (row-0
// read, L1-hot). Masked accumulate + shfl-reduce unchanged.
// ---------------------------------------------------------------------------
__global__ __launch_bounds__(256) void k_gather(
    const int* __restrict__ cnt, const int* __restrict__ slots,
    const unsigned short* __restrict__ xh, unsigned short* __restrict__ agg)
{
    int wv = threadIdx.x >> 6, ln = threadIdx.x & 63;
    int node = blockIdx.x * 4 + wv;
    int es = ln >> 4;          // edge slot 0..3 (also output rel)
    int fq = ln & 15;          // feature quarter 0..15

    int deg = cnt[node];
    int m = (deg < CAP) ? deg : CAP;
    float inv = 1.0f / fmaxf((float)deg, 1.0f);

    int sv = slots[(node << 5) + (ln & 31)];   // coalesced full-row load

    __half2 a0_01 = asH2(0), a0_23 = asH2(0);
    __half2 a1_01 = asH2(0), a1_23 = asH2(0);
    __half2 a2_01 = asH2(0), a2_23 = asH2(0);
    __half2 a3_01 = asH2(0), a3_23 = asH2(0);

    const unsigned short* xq = xh + (fq << 2);

#define ACC(xv, p, valid)                                                 \
    {                                                                     \
        int r = (p) & 3;                                                  \
        __half2 h01 = asH2((xv).x), h23 = asH2((xv).y);                   \
        __half2 m0 = asH2(((valid) && r == 0) ? 0x3C003C00u : 0u);        \
        __half2 m1 = asH2(((valid) && r == 1) ? 0x3C003C00u : 0u);        \
        __half2 m2 = asH2(((valid) && r == 2) ? 0x3C003C00u : 0u);        \
        __half2 m3 = asH2(((valid) && r == 3) ? 0x3C003C00u : 0u);        \
        a0_01 = __hfma2(h01, m0, a0_01); a0_23 = __hfma2(h23, m0, a0_23); \
        a1_01 = __hfma2(h01, m1, a1_01); a1_23 = __hfma2(h23, m1, a1_23); \
        a2_01 = __hfma2(h01, m2, a2_01); a2_23 = __hfma2(h23, m2, a2_23); \
        a3_01 = __hfma2(h01, m3, a3_01); a3_23 = __hfma2(h23, m3, a3_23); \
    }

#define BATCH(TB)                                                         \
    {                                                                     \
        int i0 = es + ((TB + 0) << 2);                                    \
        int i1 = es + ((TB + 1) << 2);                                    \
        int i2 = es + ((TB + 2) << 2);                                    \
        int i3 = es + ((TB + 3) << 2);                                    \
        int p0 = __shfl(sv, i0), p1 = __shfl(sv, i1);                     \
        int p2 = __shfl(sv, i2), p3 = __shfl(sv, i3);                     \
        bool v0 = i0 < m, v1 = i1 < m, v2 = i2 < m, v3 = i3 < m;          \
        if (!v0) p0 = 0; if (!v1) p1 = 0;                                 \
        if (!v2) p2 = 0; if (!v3) p3 = 0;                                 \
        uint2 x0 = *(const uint2*)(xq + ((size_t)(p0 >> 2) << 6));        \
        uint2 x1 = *(const uint2*)(xq + ((size_t)(p1 >> 2) << 6));        \
        uint2 x2 = *(const uint2*)(xq + ((size_t)(p2 >> 2) << 6));        \
        uint2 x3 = *(const uint2*)(xq + ((size_t)(p3 >> 2) << 6));        \
        ACC(x0, p0, v0) ACC(x1, p1, v1) ACC(x2, p2, v2) ACC(x3, p3, v3)   \
    }

    BATCH(0)                       // t = 0..3 : deg <= 16 (~97% of nodes)
    if (m > 16) BATCH(4)           // t = 4..7 : wave-uniform tail

#undef BATCH
#undef ACC

#define REDH(a)                                                        \
    a = __hadd2(a, asH2(__shfl_xor(asU32(a), 16)));                    \
    a = __hadd2(a, asH2(__shfl_xor(asU32(a), 32)));
    REDH(a0_01) REDH(a0_23) REDH(a1_01) REDH(a1_23)
    REDH(a2_01) REDH(a2_23) REDH(a3_01) REDH(a3_23)
#undef REDH

    __half2 w01 = a0_01, w23 = a0_23;
    if (es == 1)      { w01 = a1_01; w23 = a1_23; }
    else if (es == 2) { w01 = a2_01; w23 = a2_23; }
    else if (es == 3) { w01 = a3_01; w23 = a3_23; }
    float2 f01 = __half22float2(w01);
    float2 f23 = __half22float2(w23);
    uint2 st;
    st.x = asU32(__floats2half2_rn(f01.x * inv, f01.y * inv));
    st.y = asU32(__floats2half2_rn(f23.x * inv, f23.y * inv));
    *(uint2*)(agg + (size_t)node * 256 + (ln << 2)) = st;   // k = es*64 + fq*4
}

// ---------------------------------------------------------------------------
// MFMA GEMM (f16 single pass, r24 proven): tile 128 nodes x 64 outs, 4 waves.
// A = agg/xh f16, B = wt f16; v_mfma_f32_32x32x16_f16.
// LDS rows 128B, byte ^= (row&7)<<4 swizzle on write & frag read.
// ---------------------------------------------------------------------------
__global__ __launch_bounds__(256) void k_gemm(
    const unsigned short* __restrict__ agg,
    const unsigned short* __restrict__ xh,
    const unsigned short* __restrict__ wt,
    const float* __restrict__ bias, float* __restrict__ out)
{
    __shared__ short As[128 * 64];   // [row][k] f16, swizzled (16 KB)
    __shared__ short Bs[64 * 64];    // [n][k] f16, swizzled   (8 KB)

    int tid = threadIdx.x;
    int n0 = blockIdx.x * 128;
    int lane = tid & 63, wv = tid >> 6;
    int lr = lane & 31, g = lane >> 5;

    f32x16 acc0 = {}, acc1 = {};

    for (int kc = 0; kc < 5; ++kc) {
        if (kc) __syncthreads();
        // stage A: 128 rows x 64 k = 16 KB
        #pragma unroll
        for (int i = 0; i < 4; ++i) {
            int u = i * 256 + tid;
            int row = u >> 3, i16 = u & 7;
            int node = n0 + row;
            if (node > N_NODES - 1) node = N_NODES - 1;   // clamp (epilogue guards)
            const unsigned short* src = (kc < 4)
                ? (agg + (size_t)node * 256 + kc * 64)
                : (xh + (size_t)node * 64);
            u16x8 v = *(const u16x8*)(src + i16 * 8);
            int off = row * 128 + ((i16 * 16) ^ ((row & 7) << 4));
            *(u16x8*)((char*)As + off) = v;
        }
        // stage B: 64 n x 64 k
        #pragma unroll
        for (int i = 0; i < 2; ++i) {
            int u = i * 256 + tid;
            int n = u >> 3, i16 = u & 7;
            size_t s = (size_t)n * 320 + kc * 64 + i16 * 8;
            int off = n * 128 + ((i16 * 16) ^ ((n & 7) << 4));
            *(u16x8*)((char*)Bs + off) = *(const u16x8*)(wt + s);
        }
        __syncthreads();
        int ar = wv * 32 + lr;
        #pragma unroll
        for (int kst = 0; kst < 4; ++kst) {
            int kb = kst * 32 + g * 16;               // byte offset in 128B row
            int offA = ar * 128 + (kb ^ ((ar & 7) << 4));
            int offB = lr * 128 + (kb ^ ((lr & 7) << 4));
            f16x8 ah = *(const f16x8*)((const char*)As + offA);
            f16x8 b0 = *(const f16x8*)((const char*)Bs + offB);
            f16x8 b1 = *(const f16x8*)((const char*)Bs + offB + 32 * 128);
            acc0 = __builtin_amdgcn_mfma_f32_32x32x16_f16(ah, b0, acc0, 0, 0, 0);
            acc1 = __builtin_amdgcn_mfma_f32_32x32x16_f16(ah, b1, acc1, 0, 0, 0);
        }
    }

    // epilogue: C/D layout col=lane&31, row=(reg&3)+8*(reg>>2)+4*g (m74/m101)
    float b0 = bias[lr], b1 = bias[32 + lr];
    #pragma unroll
    for (int r = 0; r < 16; ++r) {
        int rowl = (r & 3) + ((r >> 2) << 3) + (g << 2);
        int node = n0 + wv * 32 + rowl;
        if (node < N_NODES) {
            out[(size_t)node * 64 + lr]      = tanhf(acc0[r] + b0);
            out[(size_t)node * 64 + 32 + lr] = tanhf(acc1[r] + b1);
        }
    }
}

extern "C" void kernel_launch(void* const* d_in, const int* in_sizes, int n_in,
                              void* d_out, int out_size, void* d_ws, size_t ws_size,
                              hipStream_t stream) {
    const float* x      = (const float*)d_in[0];
    const int*   ei     = (const int*)d_in[1];   // [2, E]
    const int*   et     = (const int*)d_in[2];   // [E]
    const float* weight = (const float*)d_in[3]; // [4,64,64]
    const float* root   = (const float*)d_in[4]; // [64,64]
    const float* bias   = (const float*)d_in[5]; // [64]
    float* out = (float*)d_out;

    // d_ws layout (~82 MB):
    unsigned short* agg = (unsigned short*)d_ws;            // N*256 f16 (51.2 MB)
    unsigned short* xh  = agg + (size_t)N_NODES * 256;      // N*64 f16  (12.8 MB)
    unsigned short* wt  = xh + (size_t)N_NODES * 64;        // 64*320 f16
    int* cnt   = (int*)(wt + 64 * 320);                     // N ints (0.4 MB)
    int* slots = cnt + N_NODES;                             // N*CAP ints (12.8 MB)
    int* qcnt  = slots + (size_t)N_NODES * CAP;             // 512 ints
    unsigned int* queue = (unsigned int*)(qcnt + NB_BKT);   // 512*2304 u32 (4.7 MB)

    hipMemsetAsync(qcnt, 0, NB_BKT * sizeof(int), stream);
    k_prepA<<<BINA_BLOCKS + PREP_BLOCKS, 512, 0, stream>>>(
        x, weight, root, ei, et, xh, wt, qcnt, queue);
    k_binB<<<NB_BKT, 256, 0, stream>>>(qcnt, queue, cnt, slots);
    k_gather<<<N_NODES / 4, 256, 0, stream>>>(cnt, slots, xh, agg);
    k_gemm<<<(N_NODES + 127) / 128, 256, 0, stream>>>(agg, xh, wt, bias, out);
}

// Round 27
// 83.587 us; speedup vs baseline: 1.1249x; 1.0171x over previous
//
#include <hip/hip_runtime.h>
#include <hip/hip_fp16.h>
#include <math.h>

#define N_NODES 100000
#define N_EDGES 1000000
#define IN_DIM 64
#define OUT_DIM 64
#define CAP 32        // per-dst slots = 2 cache lines
#define NB_BKT 512    // binning buckets; one binB block per bucket
#define DPB 196       // dsts per bucket; 512*196 >= N
#define QB 2304       // records per bucket (mean 1953 + 8 sigma)
#define BINA_BLOCKS 256    // 512 threads each; chunk 3907 (r22 proven)
#define BINA_CHUNK 3907
#define PREP_BLOCKS 3125   // (N*16)/512 4-elem units

typedef __attribute__((ext_vector_type(8)))  _Float16 f16x8;
typedef __attribute__((ext_vector_type(16))) float f32x16;
typedef __attribute__((ext_vector_type(8)))  unsigned short u16x8;
typedef __attribute__((ext_vector_type(4)))  unsigned short u16x4;

__device__ __forceinline__ __half2 asH2(unsigned int u) {
    union { unsigned int u; __half2 h; } c; c.u = u; return c.h;
}
__device__ __forceinline__ unsigned int asU32(__half2 h) {
    union { unsigned int u; __half2 h; } c; c.h = h; return c.u;
}

// ---------------------------------------------------------------------------
// Merged prepA: blocks [0,256) = binA (r22 proven body); rest = prep
// (W -> f16, x -> f16 rows). qcnt zeroed by hipMemsetAsync.
// ---------------------------------------------------------------------------
__global__ __launch_bounds__(512) void k_prepA(
    const float* __restrict__ x,
    const float* __restrict__ weight, const float* __restrict__ root,
    const int* __restrict__ ei, const int* __restrict__ et,
    unsigned short* __restrict__ xh, unsigned short* __restrict__ wt,
    int* __restrict__ qcnt, unsigned int* __restrict__ queue)
{
    __shared__ int hist[NB_BKT], base[NB_BKT], cur[NB_BKT];
    int tid = threadIdx.x;

    if (blockIdx.x < BINA_BLOCKS) {
        // ---- binA ----
        for (int b = tid; b < NB_BKT; b += 512) { hist[b] = 0; cur[b] = 0; }
        __syncthreads();
        int b0 = blockIdx.x * BINA_CHUNK;
        int b1 = b0 + BINA_CHUNK; if (b1 > N_EDGES) b1 = N_EDGES;
        for (int e = b0 + tid; e < b1; e += 512)
            atomicAdd(&hist[ei[N_EDGES + e] / DPB], 1);
        __syncthreads();
        for (int b = tid; b < NB_BKT; b += 512)
            base[b] = atomicAdd(&qcnt[b], hist[b]);
        __syncthreads();
        for (int e = b0 + tid; e < b1; e += 512) {
            int d = ei[N_EDGES + e];
            int bkt = d / DPB;
            int ld = d - bkt * DPB;                    // 0..195
            int pos = base[bkt] + atomicAdd(&cur[bkt], 1);
            if (pos < QB) {
                queue[(size_t)bkt * QB + pos] =
                    ((unsigned)ld << 19) | (unsigned)((ei[e] << 2) | (et[e] & 3));
            }
        }
    } else {
        // ---- prep ----
        int u = (blockIdx.x - BINA_BLOCKS) * 512 + tid;   // 4-elem unit
        if (u < 64 * 320) {                               // W -> f16 [n][k]
            int n = u / 320, k = u - n * 320;
            float v = (k < 256) ? weight[k * 64 + n] : root[(k - 256) * 64 + n];
            union { __half h; unsigned short s; } c; c.h = __float2half_rn(v);
            wt[u] = c.s;
        }
        if (u < N_NODES * 16) {
            float4 v = *(const float4*)(x + (size_t)u * 4);
            uint2 st;
            st.x = asU32(__floats2half2_rn(v.x, v.y));
            st.y = asU32(__floats2half2_rn(v.z, v.w));
            *(uint2*)(xh + (size_t)u * 4) = st;
        }
    }
}

// ---------------------------------------------------------------------------
// binB (r22 proven single-pass): one block per bucket; decode 4B records;
// assemble slot rows in LDS; dense writeout.
// ---------------------------------------------------------------------------
__global__ __launch_bounds__(256) void k_binB(const int* __restrict__ qcnt,
                                              const unsigned int* __restrict__ queue,
                                              int* __restrict__ cnt,
                                              int* __restrict__ slots) {
    __shared__ int lcnt[DPB];
    __shared__ int lslot[DPB * CAP];   // 25 KB
    int tid = threadIdx.x;
    int bkt = blockIdx.x;
    int d0 = bkt * DPB;
    for (int i = tid; i < DPB; i += 256) lcnt[i] = 0;
    __syncthreads();
    int n = qcnt[bkt]; if (n > QB) n = QB;
    const unsigned int* q = queue + (size_t)bkt * QB;
    for (int i = tid; i < n; i += 256) {
        unsigned int r = q[i];
        int d = (int)(r >> 19);                 // local_d 0..DPB-1
        int pos = atomicAdd(&lcnt[d], 1);
        if (pos < CAP) lslot[(d << 5) + pos] = (int)(r & 0x7ffffu);
    }
    __syncthreads();
    for (int i = tid; i < DPB; i += 256) {
        int g = d0 + i;
        if (g < N_NODES) cnt[g] = lcnt[i];
    }
    for (int i = tid; i < DPB * CAP / 4; i += 256) {
        int g0 = d0 * CAP + i * 4;
        if (g0 < N_NODES * CAP) {
            int4 v = *(const int4*)&lslot[i * 4];
            *(int4*)&slots[g0] = v;
        }
    }
}

// ---------------------------------------------------------------------------
// Gather v2 (r26 post-mortem: batch-4 captured all of ONE node's useful MLP
// for deg<=16; deeper useful MLP must come from MULTIPLE nodes). TWO NODES
// PER WAVE: both nodes' batch-1 loads issued back-to-back (8 in flight),
// then both accumulate; conditional per-node tails for deg>16. Wave count
// halves (50K, still ample TLP); per-wave fixed costs amortize over 2 nodes.
// ---------------------------------------------------------------------------
__global__ __launch_bounds__(256) void k_gather(
    const int* __restrict__ cnt, const int* __restrict__ slots,
    const unsigned short* __restrict__ xh, unsigned short* __restrict__ agg)
{
    int wv = threadIdx.x >> 6, ln = threadIdx.x & 63;
    int nA = blockIdx.x * 8 + wv * 2;      // nodes {nA, nA+1}
    int nB = nA + 1;
    int es = ln >> 4;          // edge slot 0..3 (also output rel)
    int fq = ln & 15;          // feature quarter 0..15

    int degA = cnt[nA], degB = cnt[nB];
    int mA = (degA < CAP) ? degA : CAP;
    int mB = (degB < CAP) ? degB : CAP;
    float invA = 1.0f / fmaxf((float)degA, 1.0f);
    float invB = 1.0f / fmaxf((float)degB, 1.0f);

    int svA = slots[(nA << 5) + (ln & 31)];
    int svB = slots[(nB << 5) + (ln & 31)];

    __half2 aA0_01 = asH2(0), aA0_23 = asH2(0);
    __half2 aA1_01 = asH2(0), aA1_23 = asH2(0);
    __half2 aA2_01 = asH2(0), aA2_23 = asH2(0);
    __half2 aA3_01 = asH2(0), aA3_23 = asH2(0);
    __half2 aB0_01 = asH2(0), aB0_23 = asH2(0);
    __half2 aB1_01 = asH2(0), aB1_23 = asH2(0);
    __half2 aB2_01 = asH2(0), aB2_23 = asH2(0);
    __half2 aB3_01 = asH2(0), aB3_23 = asH2(0);

    const unsigned short* xq = xh + (fq << 2);

#define ACCN(S, xv, p, valid)                                               \
    {                                                                       \
        int r = (p) & 3;                                                    \
        __half2 h01 = asH2((xv).x), h23 = asH2((xv).y);                     \
        __half2 q0 = asH2(((valid) && r == 0) ? 0x3C003C00u : 0u);          \
        __half2 q1 = asH2(((valid) && r == 1) ? 0x3C003C00u : 0u);          \
        __half2 q2 = asH2(((valid) && r == 2) ? 0x3C003C00u : 0u);          \
        __half2 q3 = asH2(((valid) && r == 3) ? 0x3C003C00u : 0u);          \
        a##S##0_01 = __hfma2(h01, q0, a##S##0_01);                          \
        a##S##0_23 = __hfma2(h23, q0, a##S##0_23);                          \
        a##S##1_01 = __hfma2(h01, q1, a##S##1_01);                          \
        a##S##1_23 = __hfma2(h23, q1, a##S##1_23);                          \
        a##S##2_01 = __hfma2(h01, q2, a##S##2_01);                          \
        a##S##2_23 = __hfma2(h23, q2, a##S##2_23);                          \
        a##S##3_01 = __hfma2(h01, q3, a##S##3_01);                          \
        a##S##3_23 = __hfma2(h23, q3, a##S##3_23);                          \
    }

#define BLOAD(S, SV, M, TB)                                                 \
    int i##S##0 = es + ((TB + 0) << 2);                                     \
    int i##S##1 = es + ((TB + 1) << 2);                                     \
    int i##S##2 = es + ((TB + 2) << 2);                                     \
    int i##S##3 = es + ((TB + 3) << 2);                                     \
    int p##S##0 = __shfl(SV, i##S##0), p##S##1 = __shfl(SV, i##S##1);       \
    int p##S##2 = __shfl(SV, i##S##2), p##S##3 = __shfl(SV, i##S##3);       \
    bool v##S##0 = i##S##0 < (M), v##S##1 = i##S##1 < (M);                  \
    bool v##S##2 = i##S##2 < (M), v##S##3 = i##S##3 < (M);                  \
    if (!v##S##0) p##S##0 = 0; if (!v##S##1) p##S##1 = 0;                   \
    if (!v##S##2) p##S##2 = 0; if (!v##S##3) p##S##3 = 0;                   \
    uint2 x##S##0 = *(const uint2*)(xq + ((size_t)(p##S##0 >> 2) << 6));    \
    uint2 x##S##1 = *(const uint2*)(xq + ((size_t)(p##S##1 >> 2) << 6));    \
    uint2 x##S##2 = *(const uint2*)(xq + ((size_t)(p##S##2 >> 2) << 6));    \
    uint2 x##S##3 = *(const uint2*)(xq + ((size_t)(p##S##3 >> 2) << 6));

#define BACC(S)                                                             \
    ACCN(S, x##S##0, p##S##0, v##S##0)                                      \
    ACCN(S, x##S##1, p##S##1, v##S##1)                                      \
    ACCN(S, x##S##2, p##S##2, v##S##2)                                      \
    ACCN(S, x##S##3, p##S##3, v##S##3)

    {   // batch 1 for both nodes: 8 loads in flight
        BLOAD(A, svA, mA, 0)
        BLOAD(B, svB, mB, 0)
        BACC(A)
        BACC(B)
    }
    if (mA > 16) { BLOAD(A, svA, mA, 4) BACC(A) }   // tails (~3% of nodes)
    if (mB > 16) { BLOAD(B, svB, mB, 4) BACC(B) }

#undef BLOAD
#undef BACC
#undef ACCN

#define REDH(a)                                                        \
    a = __hadd2(a, asH2(__shfl_xor(asU32(a), 16)));                    \
    a = __hadd2(a, asH2(__shfl_xor(asU32(a), 32)));
    REDH(aA0_01) REDH(aA0_23) REDH(aA1_01) REDH(aA1_23)
    REDH(aA2_01) REDH(aA2_23) REDH(aA3_01) REDH(aA3_23)
    REDH(aB0_01) REDH(aB0_23) REDH(aB1_01) REDH(aB1_23)
    REDH(aB2_01) REDH(aB2_23) REDH(aB3_01) REDH(aB3_23)
#undef REDH

    __half2 wA01 = aA0_01, wA23 = aA0_23;
    __half2 wB01 = aB0_01, wB23 = aB0_23;
    if (es == 1)      { wA01 = aA1_01; wA23 = aA1_23; wB01 = aB1_01; wB23 = aB1_23; }
    else if (es == 2) { wA01 = aA2_01; wA23 = aA2_23; wB01 = aB2_01; wB23 = aB2_23; }
    else if (es == 3) { wA01 = aA3_01; wA23 = aA3_23; wB01 = aB3_01; wB23 = aB3_23; }
    float2 fA01 = __half22float2(wA01);
    float2 fA23 = __half22float2(wA23);
    float2 fB01 = __half22float2(wB01);
    float2 fB23 = __half22float2(wB23);
    uint2 stA, stB;
    stA.x = asU32(__floats2half2_rn(fA01.x * invA, fA01.y * invA));
    stA.y = asU32(__floats2half2_rn(fA23.x * invA, fA23.y * invA));
    stB.x = asU32(__floats2half2_rn(fB01.x * invB, fB01.y * invB));
    stB.y = asU32(__floats2half2_rn(fB23.x * invB, fB23.y * invB));
    *(uint2*)(agg + (size_t)nA * 256 + (ln << 2)) = stA;   // k = es*64 + fq*4
    *(uint2*)(agg + (size_t)nB * 256 + (ln << 2)) = stB;
}

// ---------------------------------------------------------------------------
// MFMA GEMM (f16 single pass, r24 proven): tile 128 nodes x 64 outs, 4 waves.
// A = agg/xh f16, B = wt f16; v_mfma_f32_32x32x16_f16.
// LDS rows 128B, byte ^= (row&7)<<4 swizzle on write & frag read.
// ---------------------------------------------------------------------------
__global__ __launch_bounds__(256) void k_gemm(
    const unsigned short* __restrict__ agg,
    const unsigned short* __restrict__ xh,
    const unsigned short* __restrict__ wt,
    const float* __restrict__ bias, float* __restrict__ out)
{
    __shared__ short As[128 * 64];   // [row][k] f16, swizzled (16 KB)
    __shared__ short Bs[64 * 64];    // [n][k] f16, swizzled   (8 KB)

    int tid = threadIdx.x;
    int n0 = blockIdx.x * 128;
    int lane = tid & 63, wv = tid >> 6;
    int lr = lane & 31, g = lane >> 5;

    f32x16 acc0 = {}, acc1 = {};

    for (int kc = 0; kc < 5; ++kc) {
        if (kc) __syncthreads();
        // stage A: 128 rows x 64 k = 16 KB
        #pragma unroll
        for (int i = 0; i < 4; ++i) {
            int u = i * 256 + tid;
            int row = u >> 3, i16 = u & 7;
            int node = n0 + row;
            if (node > N_NODES - 1) node = N_NODES - 1;   // clamp (epilogue guards)
            const unsigned short* src = (kc < 4)
                ? (agg + (size_t)node * 256 + kc * 64)
                : (xh + (size_t)node * 64);
            u16x8 v = *(const u16x8*)(src + i16 * 8);
            int off = row * 128 + ((i16 * 16) ^ ((row & 7) << 4));
            *(u16x8*)((char*)As + off) = v;
        }
        // stage B: 64 n x 64 k
        #pragma unroll
        for (int i = 0; i < 2; ++i) {
            int u = i * 256 + tid;
            int n = u >> 3, i16 = u & 7;
            size_t s = (size_t)n * 320 + kc * 64 + i16 * 8;
            int off = n * 128 + ((i16 * 16) ^ ((n & 7) << 4));
            *(u16x8*)((char*)Bs + off) = *(const u16x8*)(wt + s);
        }
        __syncthreads();
        int ar = wv * 32 + lr;
        #pragma unroll
        for (int kst = 0; kst < 4; ++kst) {
            int kb = kst * 32 + g * 16;               // byte offset in 128B row
            int offA = ar * 128 + (kb ^ ((ar & 7) << 4));
            int offB = lr * 128 + (kb ^ ((lr & 7) << 4));
            f16x8 ah = *(const f16x8*)((const char*)As + offA);
            f16x8 b0 = *(const f16x8*)((const char*)Bs + offB);
            f16x8 b1 = *(const f16x8*)((const char*)Bs + offB + 32 * 128);
            acc0 = __builtin_amdgcn_mfma_f32_32x32x16_f16(ah, b0, acc0, 0, 0, 0);
            acc1 = __builtin_amdgcn_mfma_f32_32x32x16_f16(ah, b1, acc1, 0, 0, 0);
        }
    }

    // epilogue: C/D layout col=lane&31, row=(reg&3)+8*(reg>>2)+4*g (m74/m101)
    float b0 = bias[lr], b1 = bias[32 + lr];
    #pragma unroll
    for (int r = 0; r < 16; ++r) {
        int rowl = (r & 3) + ((r >> 2) << 3) + (g << 2);
        int node = n0 + wv * 32 + rowl;
        if (node < N_NODES) {
            out[(size_t)node * 64 + lr]      = tanhf(acc0[r] + b0);
            out[(size_t)node * 64 + 32 + lr] = tanhf(acc1[r] + b1);
        }
    }
}

extern "C" void kernel_launch(void* const* d_in, const int* in_sizes, int n_in,
                              void* d_out, int out_size, void* d_ws, size_t ws_size,
                              hipStream_t stream) {
    const float* x      = (const float*)d_in[0];
    const int*   ei     = (const int*)d_in[1];   // [2, E]
    const int*   et     = (const int*)d_in[2];   // [E]
    const float* weight = (const float*)d_in[3]; // [4,64,64]
    const float* root   = (const float*)d_in[4]; // [64,64]
    const float* bias   = (const float*)d_in[5]; // [64]
    float* out = (float*)d_out;

    // d_ws layout (~82 MB):
    unsigned short* agg = (unsigned short*)d_ws;            // N*256 f16 (51.2 MB)
    unsigned short* xh  = agg + (size_t)N_NODES * 256;      // N*64 f16  (12.8 MB)
    unsigned short* wt  = xh + (size_t)N_NODES * 64;        // 64*320 f16
    int* cnt   = (int*)(wt + 64 * 320);                     // N ints (0.4 MB)
    int* slots = cnt + N_NODES;                             // N*CAP ints (12.8 MB)
    int* qcnt  = slots + (size_t)N_NODES * CAP;             // 512 ints
    unsigned int* queue = (unsigned int*)(qcnt + NB_BKT);   // 512*2304 u32 (4.7 MB)

    hipMemsetAsync(qcnt, 0, NB_BKT * sizeof(int), stream);
    k_prepA<<<BINA_BLOCKS + PREP_BLOCKS, 512, 0, stream>>>(
        x, weight, root, ei, et, xh, wt, qcnt, queue);
    k_binB<<<NB_BKT, 256, 0, stream>>>(qcnt, queue, cnt, slots);
    k_gather<<<N_NODES / 8, 256, 0, stream>>>(cnt, slots, xh, agg);
    k_gemm<<<(N_NODES + 127) / 128, 256, 0, stream>>>(agg, xh, wt, bias, out);
}